// Round 7
// baseline (67.680 us; speedup 1.0000x reference)
//
#include <hip/hip_runtime.h>
#include <hip/hip_bf16.h>

constexpr int B   = 8;
constexpr int N   = 1024;
constexpr int DIN = 128;
constexpr int H   = 8;
constexpr int D   = 16;
constexpr int HD  = 128;   // H*D
constexpr int TI  = 16;    // i-rows per k_attn wave (MFMA M)
constexpr int TJ  = 128;   // j-tile
constexpr int NT  = N / TJ;

#define LOG2E 1.4426950408889634f
#define TCLAMP 30.0f       // never binds on real data (|s·log2e| < ~5)

typedef __attribute__((ext_vector_type(8))) short bf16x8;  // MFMA A/B frag
typedef __attribute__((ext_vector_type(4))) float f32x4;   // MFMA C/D frag

__device__ inline float fast_exp2(float x) {
#if __has_builtin(__builtin_amdgcn_exp2f)
    return __builtin_amdgcn_exp2f(x);
#else
    return exp2f(x);
#endif
}

// ---------------------------------------------------------------------------
// Kernel 1: MFMA projection. Block = 32 rows (grid 256 = all CUs), 256 thr.
//   Wh = h @ W (bf16 MFMA, f32 acc) -> WhT bf16 [b][c][n]
//   tI/tJ[b][h][n] = (Wh . a_src/dst) * log2e, clamped
// wave w: rows (w>>1)*16, cols (w&1)*64 (4 frags).
// ---------------------------------------------------------------------------
__global__ __launch_bounds__(256) void k_proj(
    const float* __restrict__ hsrc,
    const float* __restrict__ W,
    const float* __restrict__ a,
    __hip_bfloat16* __restrict__ WhT,  // [B][HD][N]
    float* __restrict__ tI,            // [B][H][N]
    float* __restrict__ tJ)            // [B][H][N]
{
    const int row0 = blockIdx.x * 32;    // global row (b*N+n)
    const int b    = row0 >> 10;
    const int n0   = row0 & (N - 1);
    const int t    = threadIdx.x;
    const int lane = t & 63, wave = t >> 6;
    const int mn   = lane & 15, kg = lane >> 4;

    __shared__ __align__(16) __hip_bfloat16 hA[32][136];   // [row][k]
    __shared__ __align__(16) __hip_bfloat16 Wt[128][136];  // [col][k]

    // stage h-tile (32x128 f32 -> bf16)
    {
        const float4* hf = reinterpret_cast<const float4*>(hsrc + (size_t)row0 * DIN);
        #pragma unroll
        for (int u = 0; u < 4; ++u) {
            const int idx = t + u * 256;          // float4 index
            const float4 v = hf[idx];
            const int r = idx >> 5, c4 = (idx & 31) * 4;
            hA[r][c4]     = __float2bfloat16(v.x);
            hA[r][c4 + 1] = __float2bfloat16(v.y);
            hA[r][c4 + 2] = __float2bfloat16(v.z);
            hA[r][c4 + 3] = __float2bfloat16(v.w);
        }
    }
    // stage W transposed (128x128 f32 [k][c] -> bf16 [c][k])
    {
        const float4* wf = reinterpret_cast<const float4*>(W);
        #pragma unroll
        for (int u = 0; u < 16; ++u) {
            const int idx = t + u * 256;
            const float4 v = wf[idx];
            const int k = idx >> 5, c0 = (idx & 31) * 4;
            Wt[c0][k]     = __float2bfloat16(v.x);
            Wt[c0 + 1][k] = __float2bfloat16(v.y);
            Wt[c0 + 2][k] = __float2bfloat16(v.z);
            Wt[c0 + 3][k] = __float2bfloat16(v.w);
        }
    }
    __syncthreads();

    const int lr0 = (wave >> 1) * 16;       // row offset of this wave
    const int ch  = wave & 1;               // col half (64 cols)
    f32x4 acc[4];
    #pragma unroll
    for (int f = 0; f < 4; ++f) acc[f] = (f32x4){0.f, 0.f, 0.f, 0.f};

    #pragma unroll
    for (int kk = 0; kk < 4; ++kk) {
        const bf16x8 af = *reinterpret_cast<const bf16x8*>(
            &hA[lr0 + mn][kk * 32 + kg * 8]);
        #pragma unroll
        for (int f = 0; f < 4; ++f) {
            const bf16x8 bf = *reinterpret_cast<const bf16x8*>(
                &Wt[ch * 64 + f * 16 + mn][kk * 32 + kg * 8]);
            acc[f] = __builtin_amdgcn_mfma_f32_16x16x32_bf16(af, bf, acc[f], 0, 0, 0);
        }
    }

    // epilogue: WhT store + tI/tJ shuffle-reduce (head = ch*4+f, d = mn)
    #pragma unroll
    for (int f = 0; f < 4; ++f) {
        const int hh = ch * 4 + f;
        const float as = a[hh * 32 + mn];       // a[h][d]
        const float ad = a[hh * 32 + 16 + mn];  // a[h][D+d]
        #pragma unroll
        for (int r = 0; r < 4; ++r) {
            const int n = n0 + lr0 + kg * 4 + r;
            WhT[((size_t)(b * HD + ch * 64 + f * 16 + mn)) * N + n] =
                __float2bfloat16(acc[f][r]);
            float vi = acc[f][r] * as;
            float vj = acc[f][r] * ad;
            #pragma unroll
            for (int m = 1; m < 16; m <<= 1) {
                vi += __shfl_xor(vi, m);
                vj += __shfl_xor(vj, m);
            }
            if (mn == 0) {
                tI[((size_t)(b * H + hh)) * N + n] = fminf(vi * LOG2E, TCLAMP);
                tJ[((size_t)(b * H + hh)) * N + n] = fminf(vj * LOG2E, TCLAMP);
            }
        }
    }
}

// ---------------------------------------------------------------------------
// Kernel 2: fused attention — barrier-free, LDS-free. Wave = (head, i-tile).
// Lane (mn,kg) computes its OWN A-frag scores in registers (row i0+mn,
// k = kk*32+kg*8+e), exactly matching the MFMA A layout; A/B use the same
// k-position convention so any HW k-permutation self-cancels.
//   accO += P(16x32) x WhT(32x16);  accD += P x 1  (softmax denominator)
// No max subtraction (scores bounded, softmax shift-invariant).
// ---------------------------------------------------------------------------
__global__ __launch_bounds__(512, 4) void k_attn(
    const int*            __restrict__ adj,    // [B][N][N]
    const __hip_bfloat16* __restrict__ WhT,    // [B][HD][N]
    const float*          __restrict__ tI,     // [B][H][N]
    const float*          __restrict__ tJ,     // [B][H][N]
    float*                __restrict__ out)    // [B][N][HD]
{
    const int b    = blockIdx.y;
    const int i0   = blockIdx.x * TI;
    const int t    = threadIdx.x;
    const int lane = t & 63, h = t >> 6;       // wave = head
    const int mn   = lane & 15, kg = lane >> 4;

    const float Arow = tI[((size_t)(b * H + h)) * N + i0 + mn];
    const float* tjrow = tJ + ((size_t)(b * H + h)) * N;
    const int*   arow  = adj + ((size_t)(b * N) + i0 + mn) * N;
    const __hip_bfloat16* wbase =
        WhT + ((size_t)(b * HD + h * 16 + mn)) * N + kg * 8;

    f32x4 accO = {0.f, 0.f, 0.f, 0.f};
    f32x4 accD = {0.f, 0.f, 0.f, 0.f};
    bf16x8 ones;
    #pragma unroll
    for (int e = 0; e < 8; ++e) ones[e] = (short)0x3F80;   // bf16 1.0

    for (int jt = 0; jt < NT; ++jt) {
        const int j0 = jt * TJ;
        #pragma unroll
        for (int kk = 0; kk < 4; ++kk) {
            const int jb = j0 + kk * 32 + kg * 8;
            const float4 t0 = *reinterpret_cast<const float4*>(tjrow + jb);
            const float4 t1 = *reinterpret_cast<const float4*>(tjrow + jb + 4);
            const int4   a0 = *reinterpret_cast<const int4*>(arow + jb);
            const int4   a1 = *reinterpret_cast<const int4*>(arow + jb + 4);
            const bf16x8 bfr = *reinterpret_cast<const bf16x8*>(
                wbase + j0 + kk * 32);

            const float tv[8] = {t0.x, t0.y, t0.z, t0.w, t1.x, t1.y, t1.z, t1.w};
            const int   av[8] = {a0.x, a0.y, a0.z, a0.w, a1.x, a1.y, a1.z, a1.w};
            bf16x8 af;
            #pragma unroll
            for (int e = 0; e < 8; ++e) {
                const float x = Arow + tv[e];
                float s = fmaxf(x, 0.2f * x);
                s = (av[e] != 0) ? s : -1.0e30f;
                const float p = fast_exp2(s);
                af[e] = (short)__bfloat16_as_ushort(__float2bfloat16(p));
            }
            accO = __builtin_amdgcn_mfma_f32_16x16x32_bf16(af, bfr, accO, 0, 0, 0);
            accD = __builtin_amdgcn_mfma_f32_16x16x32_bf16(af, ones, accD, 0, 0, 0);
        }
    }

    // ---- normalize + store: C layout col=lane&15, row=(lane>>4)*4+reg ----
    #pragma unroll
    for (int r = 0; r < 4; ++r) {
        out[((size_t)(b * N) + i0 + kg * 4 + r) * HD + h * 16 + mn] =
            accO[r] / accD[r];
    }
}

// ---------------------------------------------------------------------------
extern "C" void kernel_launch(void* const* d_in, const int* in_sizes, int n_in,
                              void* d_out, int out_size, void* d_ws, size_t ws_size,
                              hipStream_t stream)
{
    const float* h   = (const float*)d_in[0];   // f32 (proven R3/R5)
    const int*   adj = (const int*)d_in[1];
    const float* W   = (const float*)d_in[2];
    const float* a   = (const float*)d_in[3];
    float* out = (float*)d_out;

    float* ws = (float*)d_ws;
    float* tI = ws;                              // B*H*N f32 (256 KB)
    float* tJ = ws + (size_t)B * H * N;          // B*H*N f32 (256 KB)
    __hip_bfloat16* WhT = (__hip_bfloat16*)(ws + (size_t)2 * B * H * N); // 2 MB

    k_proj<<<dim3(B * N / 32), dim3(256), 0, stream>>>(h, W, a, WhT, tI, tJ);
    k_attn<<<dim3(N / TI, B), dim3(512), 0, stream>>>(adj, WhT, tI, tJ, out);
}

// Round 8
// 67.119 us; speedup vs baseline: 1.0084x; 1.0084x over previous
//
#include <hip/hip_runtime.h>
#include <hip/hip_bf16.h>

constexpr int B   = 8;
constexpr int N   = 1024;
constexpr int DIN = 128;
constexpr int H   = 8;
constexpr int D   = 16;
constexpr int HD  = 128;   // H*D
constexpr int TI  = 16;    // i-rows per k_attn wave (MFMA M)
constexpr int NS  = N / 32; // 32 j's per pipeline step

#define LOG2E 1.4426950408889634f
#define TCLAMP 30.0f       // never binds on real data (|s·log2e| < ~5)

typedef __attribute__((ext_vector_type(8))) short bf16x8;  // MFMA A/B frag
typedef __attribute__((ext_vector_type(4))) float f32x4;   // MFMA C/D frag

__device__ inline float fast_exp2(float x) {
#if __has_builtin(__builtin_amdgcn_exp2f)
    return __builtin_amdgcn_exp2f(x);
#else
    return exp2f(x);
#endif
}

// ---------------------------------------------------------------------------
// Kernel 1: MFMA projection. Block = 32 rows (grid 256 = all CUs), 256 thr.
//   Wh = h @ W (bf16 MFMA, f32 acc) -> WhT bf16 [b][c][n]
//   tI/tJ[b][h][n] = (Wh . a_src/dst) * log2e, clamped
// ---------------------------------------------------------------------------
__global__ __launch_bounds__(256) void k_proj(
    const float* __restrict__ hsrc,
    const float* __restrict__ W,
    const float* __restrict__ a,
    __hip_bfloat16* __restrict__ WhT,  // [B][HD][N]
    float* __restrict__ tI,            // [B][H][N]
    float* __restrict__ tJ)            // [B][H][N]
{
    const int row0 = blockIdx.x * 32;    // global row (b*N+n)
    const int b    = row0 >> 10;
    const int n0   = row0 & (N - 1);
    const int t    = threadIdx.x;
    const int lane = t & 63, wave = t >> 6;
    const int mn   = lane & 15, kg = lane >> 4;

    __shared__ __align__(16) __hip_bfloat16 hA[32][136];   // [row][k]
    __shared__ __align__(16) __hip_bfloat16 Wt[128][136];  // [col][k]

    // stage h-tile (32x128 f32 -> bf16)
    {
        const float4* hf = reinterpret_cast<const float4*>(hsrc + (size_t)row0 * DIN);
        #pragma unroll
        for (int u = 0; u < 4; ++u) {
            const int idx = t + u * 256;          // float4 index
            const float4 v = hf[idx];
            const int r = idx >> 5, c4 = (idx & 31) * 4;
            hA[r][c4]     = __float2bfloat16(v.x);
            hA[r][c4 + 1] = __float2bfloat16(v.y);
            hA[r][c4 + 2] = __float2bfloat16(v.z);
            hA[r][c4 + 3] = __float2bfloat16(v.w);
        }
    }
    // stage W transposed (128x128 f32 [k][c] -> bf16 [c][k])
    {
        const float4* wf = reinterpret_cast<const float4*>(W);
        #pragma unroll
        for (int u = 0; u < 16; ++u) {
            const int idx = t + u * 256;
            const float4 v = wf[idx];
            const int k = idx >> 5, c0 = (idx & 31) * 4;
            Wt[c0][k]     = __float2bfloat16(v.x);
            Wt[c0 + 1][k] = __float2bfloat16(v.y);
            Wt[c0 + 2][k] = __float2bfloat16(v.z);
            Wt[c0 + 3][k] = __float2bfloat16(v.w);
        }
    }
    __syncthreads();

    const int lr0 = (wave >> 1) * 16;       // row offset of this wave
    const int ch  = wave & 1;               // col half (64 cols)
    f32x4 acc[4];
    #pragma unroll
    for (int f = 0; f < 4; ++f) acc[f] = (f32x4){0.f, 0.f, 0.f, 0.f};

    #pragma unroll
    for (int kk = 0; kk < 4; ++kk) {
        const bf16x8 af = *reinterpret_cast<const bf16x8*>(
            &hA[lr0 + mn][kk * 32 + kg * 8]);
        #pragma unroll
        for (int f = 0; f < 4; ++f) {
            const bf16x8 bf = *reinterpret_cast<const bf16x8*>(
                &Wt[ch * 64 + f * 16 + mn][kk * 32 + kg * 8]);
            acc[f] = __builtin_amdgcn_mfma_f32_16x16x32_bf16(af, bf, acc[f], 0, 0, 0);
        }
    }

    // epilogue: WhT store + tI/tJ shuffle-reduce (head = ch*4+f, d = mn)
    #pragma unroll
    for (int f = 0; f < 4; ++f) {
        const int hh = ch * 4 + f;
        const float as = a[hh * 32 + mn];       // a[h][d]
        const float ad = a[hh * 32 + 16 + mn];  // a[h][D+d]
        #pragma unroll
        for (int r = 0; r < 4; ++r) {
            const int n = n0 + lr0 + kg * 4 + r;
            WhT[((size_t)(b * HD + ch * 64 + f * 16 + mn)) * N + n] =
                __float2bfloat16(acc[f][r]);
            float vi = acc[f][r] * as;
            float vj = acc[f][r] * ad;
            #pragma unroll
            for (int m = 1; m < 16; m <<= 1) {
                vi += __shfl_xor(vi, m);
                vj += __shfl_xor(vj, m);
            }
            if (mn == 0) {
                tI[((size_t)(b * H + hh)) * N + n] = fminf(vi * LOG2E, TCLAMP);
                tJ[((size_t)(b * H + hh)) * N + n] = fminf(vj * LOG2E, TCLAMP);
            }
        }
    }
}

// ---------------------------------------------------------------------------
// Kernel 2: fused attention — barrier-free, LDS-free, software-pipelined.
// Block = 256 thr = 4 waves = 4 heads; blockIdx.z selects head half.
// Lane (mn,kg) builds its OWN A-frag scores in registers (row i0+mn,
// k = s*32+kg*8+e), matching the MFMA A layout; A/B share the k-position
// convention so any HW k-permutation self-cancels.
// Per step s (32 j's): prefetch step s+1's tj/adj/WhT into named registers,
// THEN compute step s's scores + 2 MFMAs (accO += P x WhT, accD += P x 1).
// No max subtraction (scores bounded; softmax shift-invariant; out=accO/accD).
// ---------------------------------------------------------------------------
__global__ __launch_bounds__(256, 4) void k_attn(
    const int*            __restrict__ adj,    // [B][N][N]
    const __hip_bfloat16* __restrict__ WhT,    // [B][HD][N]
    const float*          __restrict__ tI,     // [B][H][N]
    const float*          __restrict__ tJ,     // [B][H][N]
    float*                __restrict__ out)    // [B][N][HD]
{
    const int b    = blockIdx.y;
    const int i0   = blockIdx.x * TI;
    const int lane = threadIdx.x & 63;
    const int h    = blockIdx.z * 4 + (threadIdx.x >> 6);   // head
    const int mn   = lane & 15, kg = lane >> 4;

    const float Arow = tI[((size_t)(b * H + h)) * N + i0 + mn];
    const float* tjrow = tJ + ((size_t)(b * H + h)) * N + kg * 8;
    const int*   arow  = adj + ((size_t)(b * N) + i0 + mn) * N + kg * 8;
    const __hip_bfloat16* wrow =
        WhT + ((size_t)(b * HD + h * 16 + mn)) * N + kg * 8;

    f32x4 accO = {0.f, 0.f, 0.f, 0.f};
    f32x4 accD = {0.f, 0.f, 0.f, 0.f};
    bf16x8 ones;
    #pragma unroll
    for (int e = 0; e < 8; ++e) ones[e] = (short)0x3F80;   // bf16 1.0

    // prologue: load step 0
    float4 t0c = *reinterpret_cast<const float4*>(tjrow);
    float4 t1c = *reinterpret_cast<const float4*>(tjrow + 4);
    int4   a0c = *reinterpret_cast<const int4*>(arow);
    int4   a1c = *reinterpret_cast<const int4*>(arow + 4);
    bf16x8 wc  = *reinterpret_cast<const bf16x8*>(wrow);

    #pragma unroll 8
    for (int s = 0; s < NS - 1; ++s) {
        const int off = (s + 1) * 32;
        // ---- prefetch step s+1 (named regs -> must stay live) ----
        const float4 t0n = *reinterpret_cast<const float4*>(tjrow + off);
        const float4 t1n = *reinterpret_cast<const float4*>(tjrow + off + 4);
        const int4   a0n = *reinterpret_cast<const int4*>(arow + off);
        const int4   a1n = *reinterpret_cast<const int4*>(arow + off + 4);
        const bf16x8 wn  = *reinterpret_cast<const bf16x8*>(wrow + off);

        // ---- compute step s ----
        {
            const float tv[8] = {t0c.x, t0c.y, t0c.z, t0c.w,
                                 t1c.x, t1c.y, t1c.z, t1c.w};
            const int   av[8] = {a0c.x, a0c.y, a0c.z, a0c.w,
                                 a1c.x, a1c.y, a1c.z, a1c.w};
            bf16x8 af;
            #pragma unroll
            for (int e = 0; e < 8; ++e) {
                const float x = Arow + tv[e];
                float sc = fmaxf(x, 0.2f * x);
                sc = (av[e] != 0) ? sc : -1.0e30f;
                af[e] = (short)__bfloat16_as_ushort(
                    __float2bfloat16(fast_exp2(sc)));
            }
            accO = __builtin_amdgcn_mfma_f32_16x16x32_bf16(af, wc, accO, 0, 0, 0);
            accD = __builtin_amdgcn_mfma_f32_16x16x32_bf16(af, ones, accD, 0, 0, 0);
        }
        t0c = t0n; t1c = t1n; a0c = a0n; a1c = a1n; wc = wn;
    }

    // epilogue: step NS-1
    {
        const float tv[8] = {t0c.x, t0c.y, t0c.z, t0c.w,
                             t1c.x, t1c.y, t1c.z, t1c.w};
        const int   av[8] = {a0c.x, a0c.y, a0c.z, a0c.w,
                             a1c.x, a1c.y, a1c.z, a1c.w};
        bf16x8 af;
        #pragma unroll
        for (int e = 0; e < 8; ++e) {
            const float x = Arow + tv[e];
            float sc = fmaxf(x, 0.2f * x);
            sc = (av[e] != 0) ? sc : -1.0e30f;
            af[e] = (short)__bfloat16_as_ushort(
                __float2bfloat16(fast_exp2(sc)));
        }
        accO = __builtin_amdgcn_mfma_f32_16x16x32_bf16(af, wc, accO, 0, 0, 0);
        accD = __builtin_amdgcn_mfma_f32_16x16x32_bf16(af, ones, accD, 0, 0, 0);
    }

    // ---- normalize + store: C layout col=lane&15, row=(lane>>4)*4+reg ----
    #pragma unroll
    for (int r = 0; r < 4; ++r) {
        out[((size_t)(b * N) + i0 + kg * 4 + r) * HD + h * 16 + mn] =
            accO[r] / accD[r];
    }
}

// ---------------------------------------------------------------------------
extern "C" void kernel_launch(void* const* d_in, const int* in_sizes, int n_in,
                              void* d_out, int out_size, void* d_ws, size_t ws_size,
                              hipStream_t stream)
{
    const float* h   = (const float*)d_in[0];   // f32 (proven R3/R5)
    const int*   adj = (const int*)d_in[1];
    const float* W   = (const float*)d_in[2];
    const float* a   = (const float*)d_in[3];
    float* out = (float*)d_out;

    float* ws = (float*)d_ws;
    float* tI = ws;                              // B*H*N f32 (256 KB)
    float* tJ = ws + (size_t)B * H * N;          // B*H*N f32 (256 KB)
    __hip_bfloat16* WhT = (__hip_bfloat16*)(ws + (size_t)2 * B * H * N); // 2 MB

    k_proj<<<dim3(B * N / 32), dim3(256), 0, stream>>>(h, W, a, WhT, tI, tJ);
    k_attn<<<dim3(N / TI, B, 2), dim3(256), 0, stream>>>(adj, WhT, tI, tJ, out);
}

// Round 9
// 54.700 us; speedup vs baseline: 1.2373x; 1.2270x over previous
//
#include <hip/hip_runtime.h>
#include <hip/hip_bf16.h>

constexpr int B   = 8;
constexpr int N   = 1024;
constexpr int DIN = 128;
constexpr int H   = 8;
constexpr int D   = 16;
constexpr int HD  = 128;   // H*D
constexpr int TI  = 16;    // i-rows per k_attn wave (MFMA M)
constexpr int NS  = N / 32; // 32 j's per pipeline step

#define LOG2E 1.4426950408889634f
#define TCLAMP 30.0f       // never binds on real data (|s·log2e| < ~5)

typedef __attribute__((ext_vector_type(8))) short bf16x8;  // MFMA A/B frag
typedef __attribute__((ext_vector_type(4))) float f32x4;   // MFMA C/D frag

__device__ inline float fast_exp2(float x) {
#if __has_builtin(__builtin_amdgcn_exp2f)
    return __builtin_amdgcn_exp2f(x);
#else
    return exp2f(x);
#endif
}

// ---------------------------------------------------------------------------
// Pack adj -> bitmask [B][N][N/32] u32. One coalesced streaming pass over the
// 32 MB adj (this HBM read is unavoidable; pay it here, latency-tolerant).
// ---------------------------------------------------------------------------
__global__ __launch_bounds__(256) void k_pack(const int* __restrict__ adj,
                                              unsigned int* __restrict__ bm)
{
    const size_t g = (size_t)blockIdx.x * 256 + threadIdx.x;
    const unsigned long long m = __ballot(adj[g] != 0);
    const int l = threadIdx.x & 63;
    if (l == 0)  bm[g >> 5] = (unsigned int)m;
    if (l == 32) bm[g >> 5] = (unsigned int)(m >> 32);
}

// ---------------------------------------------------------------------------
// Kernel 1: MFMA projection. Block = 32 rows (grid 256 = all CUs), 256 thr.
//   Wh = h @ W (bf16 MFMA, f32 acc) -> WhT bf16 [b][c][n]
//   tI/tJ[b][h][n] = (Wh . a_src/dst) * log2e, clamped
// ---------------------------------------------------------------------------
__global__ __launch_bounds__(256) void k_proj(
    const float* __restrict__ hsrc,
    const float* __restrict__ W,
    const float* __restrict__ a,
    __hip_bfloat16* __restrict__ WhT,  // [B][HD][N]
    float* __restrict__ tI,            // [B][H][N]
    float* __restrict__ tJ)            // [B][H][N]
{
    const int row0 = blockIdx.x * 32;    // global row (b*N+n)
    const int b    = row0 >> 10;
    const int n0   = row0 & (N - 1);
    const int t    = threadIdx.x;
    const int lane = t & 63, wave = t >> 6;
    const int mn   = lane & 15, kg = lane >> 4;

    __shared__ __align__(16) __hip_bfloat16 hA[32][136];   // [row][k]
    __shared__ __align__(16) __hip_bfloat16 Wt[128][136];  // [col][k]

    // stage h-tile (32x128 f32 -> bf16)
    {
        const float4* hf = reinterpret_cast<const float4*>(hsrc + (size_t)row0 * DIN);
        #pragma unroll
        for (int u = 0; u < 4; ++u) {
            const int idx = t + u * 256;          // float4 index
            const float4 v = hf[idx];
            const int r = idx >> 5, c4 = (idx & 31) * 4;
            hA[r][c4]     = __float2bfloat16(v.x);
            hA[r][c4 + 1] = __float2bfloat16(v.y);
            hA[r][c4 + 2] = __float2bfloat16(v.z);
            hA[r][c4 + 3] = __float2bfloat16(v.w);
        }
    }
    // stage W transposed (128x128 f32 [k][c] -> bf16 [c][k])
    {
        const float4* wf = reinterpret_cast<const float4*>(W);
        #pragma unroll
        for (int u = 0; u < 16; ++u) {
            const int idx = t + u * 256;
            const float4 v = wf[idx];
            const int k = idx >> 5, c0 = (idx & 31) * 4;
            Wt[c0][k]     = __float2bfloat16(v.x);
            Wt[c0 + 1][k] = __float2bfloat16(v.y);
            Wt[c0 + 2][k] = __float2bfloat16(v.z);
            Wt[c0 + 3][k] = __float2bfloat16(v.w);
        }
    }
    __syncthreads();

    const int lr0 = (wave >> 1) * 16;       // row offset of this wave
    const int ch  = wave & 1;               // col half (64 cols)
    f32x4 acc[4];
    #pragma unroll
    for (int f = 0; f < 4; ++f) acc[f] = (f32x4){0.f, 0.f, 0.f, 0.f};

    #pragma unroll
    for (int kk = 0; kk < 4; ++kk) {
        const bf16x8 af = *reinterpret_cast<const bf16x8*>(
            &hA[lr0 + mn][kk * 32 + kg * 8]);
        #pragma unroll
        for (int f = 0; f < 4; ++f) {
            const bf16x8 bf = *reinterpret_cast<const bf16x8*>(
                &Wt[ch * 64 + f * 16 + mn][kk * 32 + kg * 8]);
            acc[f] = __builtin_amdgcn_mfma_f32_16x16x32_bf16(af, bf, acc[f], 0, 0, 0);
        }
    }

    // epilogue: WhT store + tI/tJ shuffle-reduce (head = ch*4+f, d = mn)
    #pragma unroll
    for (int f = 0; f < 4; ++f) {
        const int hh = ch * 4 + f;
        const float as = a[hh * 32 + mn];       // a[h][d]
        const float ad = a[hh * 32 + 16 + mn];  // a[h][D+d]
        #pragma unroll
        for (int r = 0; r < 4; ++r) {
            const int n = n0 + lr0 + kg * 4 + r;
            WhT[((size_t)(b * HD + ch * 64 + f * 16 + mn)) * N + n] =
                __float2bfloat16(acc[f][r]);
            float vi = acc[f][r] * as;
            float vj = acc[f][r] * ad;
            #pragma unroll
            for (int m = 1; m < 16; m <<= 1) {
                vi += __shfl_xor(vi, m);
                vj += __shfl_xor(vj, m);
            }
            if (mn == 0) {
                tI[((size_t)(b * H + hh)) * N + n] = fminf(vi * LOG2E, TCLAMP);
                tJ[((size_t)(b * H + hh)) * N + n] = fminf(vj * LOG2E, TCLAMP);
            }
        }
    }
}

// ---------------------------------------------------------------------------
// Kernel 2: fused attention — barrier-free, LDS-free, mask-in-register.
// Block = 256 thr = 4 waves = 4 heads; blockIdx.z selects head half.
// Lane (mn,kg) builds its OWN A-frag scores in registers (row i0+mn,
// k = s*32+kg*8+e), matching the MFMA A layout.
// Prologue: the lane's full 1024-bit adj-row mask -> 32 u32 in VGPRs.
// Per step: prefetch s+1's tj/WhT (L2-resident), fence, compute step s
// (8 lrelu+exp2 + mask-select), 2 MFMAs (accO += P x WhT, accD += P x 1).
// No max subtraction (scores bounded; softmax shift-invariant; out=accO/accD).
// ---------------------------------------------------------------------------
__global__ __launch_bounds__(256, 4) void k_attn(
    const unsigned int*   __restrict__ bm,     // [B][N][N/32]
    const __hip_bfloat16* __restrict__ WhT,    // [B][HD][N]
    const float*          __restrict__ tI,     // [B][H][N]
    const float*          __restrict__ tJ,     // [B][H][N]
    float*                __restrict__ out)    // [B][N][HD]
{
    const int b    = blockIdx.y;
    const int i0   = blockIdx.x * TI;
    const int lane = threadIdx.x & 63;
    const int h    = blockIdx.z * 4 + (threadIdx.x >> 6);   // head
    const int mn   = lane & 15, kg = lane >> 4;

    const float Arow = tI[((size_t)(b * H + h)) * N + i0 + mn];
    const float* tjrow = tJ + ((size_t)(b * H + h)) * N + kg * 8;
    const __hip_bfloat16* wrow =
        WhT + ((size_t)(b * HD + h * 16 + mn)) * N + kg * 8;
    const unsigned int* brow = bm + ((size_t)(b * N) + i0 + mn) * (N / 32);

    // prologue: whole row mask into registers (8 x uint4 = 32 words)
    unsigned int mw[NS];
    {
        const uint4* bq = reinterpret_cast<const uint4*>(brow);
        #pragma unroll
        for (int u = 0; u < 8; ++u) {
            const uint4 v = bq[u];
            mw[4 * u + 0] = v.x; mw[4 * u + 1] = v.y;
            mw[4 * u + 2] = v.z; mw[4 * u + 3] = v.w;
        }
    }

    f32x4 accO = {0.f, 0.f, 0.f, 0.f};
    f32x4 accD = {0.f, 0.f, 0.f, 0.f};
    bf16x8 ones;
    #pragma unroll
    for (int e = 0; e < 8; ++e) ones[e] = (short)0x3F80;   // bf16 1.0

    // step-0 loads
    float4 t0c = *reinterpret_cast<const float4*>(tjrow);
    float4 t1c = *reinterpret_cast<const float4*>(tjrow + 4);
    bf16x8 wc  = *reinterpret_cast<const bf16x8*>(wrow);

    #pragma unroll
    for (int s = 0; s < NS; ++s) {
        float4 t0n, t1n; bf16x8 wn;
        if (s < NS - 1) {
            const int off = (s + 1) * 32;
            t0n = *reinterpret_cast<const float4*>(tjrow + off);
            t1n = *reinterpret_cast<const float4*>(tjrow + off + 4);
            wn  = *reinterpret_cast<const bf16x8*>(wrow + off);
            asm volatile("" ::: "memory");   // pin prefetch issue before compute
        }

        const unsigned int m8 = (mw[s] >> (kg * 8)) & 0xFFu;
        const float tv[8] = {t0c.x, t0c.y, t0c.z, t0c.w,
                             t1c.x, t1c.y, t1c.z, t1c.w};
        bf16x8 af;
        #pragma unroll
        for (int e = 0; e < 8; ++e) {
            const float x = Arow + tv[e];
            float sc = fmaxf(x, 0.2f * x);
            sc = ((m8 >> e) & 1u) ? sc : -1.0e30f;
            af[e] = (short)__bfloat16_as_ushort(
                __float2bfloat16(fast_exp2(sc)));
        }
        accO = __builtin_amdgcn_mfma_f32_16x16x32_bf16(af, wc, accO, 0, 0, 0);
        accD = __builtin_amdgcn_mfma_f32_16x16x32_bf16(af, ones, accD, 0, 0, 0);

        if (s < NS - 1) { t0c = t0n; t1c = t1n; wc = wn; }
    }

    // ---- normalize + store: C layout col=lane&15, row=(lane>>4)*4+reg ----
    #pragma unroll
    for (int r = 0; r < 4; ++r) {
        out[((size_t)(b * N) + i0 + kg * 4 + r) * HD + h * 16 + mn] =
            accO[r] / accD[r];
    }
}

// ---------------------------------------------------------------------------
extern "C" void kernel_launch(void* const* d_in, const int* in_sizes, int n_in,
                              void* d_out, int out_size, void* d_ws, size_t ws_size,
                              hipStream_t stream)
{
    const float* h   = (const float*)d_in[0];   // f32 (proven R3/R5)
    const int*   adj = (const int*)d_in[1];
    const float* W   = (const float*)d_in[2];
    const float* a   = (const float*)d_in[3];
    float* out = (float*)d_out;

    float* ws = (float*)d_ws;
    float* tI = ws;                              // B*H*N f32 (256 KB)
    float* tJ = ws + (size_t)B * H * N;          // B*H*N f32 (256 KB)
    __hip_bfloat16* WhT = (__hip_bfloat16*)(ws + (size_t)2 * B * H * N); // 2 MB
    unsigned int* bm = (unsigned int*)((char*)WhT +
                       (size_t)B * N * HD * sizeof(__hip_bfloat16));     // 1 MB

    k_pack<<<dim3((B * N * N) / 256), dim3(256), 0, stream>>>(adj, bm);
    k_proj<<<dim3(B * N / 32), dim3(256), 0, stream>>>(h, W, a, WhT, tI, tJ);
    k_attn<<<dim3(N / TI, B, 2), dim3(256), 0, stream>>>(bm, WhT, tI, tJ, out);
}